// Round 2
// baseline (642.651 us; speedup 1.0000x reference)
//
#include <hip/hip_runtime.h>
#include <hip/hip_bf16.h>
#include <type_traits>

#define BATCH  16
#define SEQ    1024
#define HIDDEN 1024
#define NHEAD  4
#define DHEAD  256
#define QKVN   2304   // (2*NHEAD+1)*DHEAD

typedef _Float16 f16x8 __attribute__((ext_vector_type(8)));
typedef float    f32x4 __attribute__((ext_vector_type(4)));

__device__ __forceinline__ void gll16(const void* g, void* l) {
  __builtin_amdgcn_global_load_lds(
      (const __attribute__((address_space(1))) unsigned int*)g,
      (__attribute__((address_space(3))) unsigned int*)l, 16, 0, 0);
}

// ---------------------------------------------------------------------------
// fp32 -> f16 elementwise (x pre-conversion)
// ---------------------------------------------------------------------------
__global__ __launch_bounds__(256) void f32_to_f16(
    const float* __restrict__ in, _Float16* __restrict__ out) {
  int i4 = blockIdx.x * 256 + threadIdx.x;
  float4 v = ((const float4*)in)[i4];
  _Float16 h4[4] = {(_Float16)v.x, (_Float16)v.y, (_Float16)v.z, (_Float16)v.w};
  *(uint2*)&out[(size_t)i4 * 4] = *(uint2*)h4;
}

// ---------------------------------------------------------------------------
// Transpose fp32 [R][C] -> f16 [C][R]
// ---------------------------------------------------------------------------
__global__ __launch_bounds__(256) void transpose_to_f16(
    const float* __restrict__ in, _Float16* __restrict__ out, int R, int C) {
  __shared__ float tile[64][65];
  int bc = blockIdx.x * 64, br = blockIdx.y * 64;
  int t = threadIdx.x;
  int tr = t >> 6, tc = t & 63;
  for (int i = 0; i < 64; i += 4)
    tile[tr + i][tc] = in[(size_t)(br + tr + i) * C + bc + tc];
  __syncthreads();
  for (int i = 0; i < 64; i += 4)
    out[(size_t)(bc + tr + i) * R + br + tc] = (_Float16)tile[tc][tr + i];
}

// ---------------------------------------------------------------------------
// 256x256-tile 8-phase GEMM (B^T): C[m][n] = sum_k A[m][k]*B[n][k], f16 in.
// 512 thr = 8 waves (2M x 4N), BK=64, 128 KiB LDS double-buffer.
// Per K-tile: 4 phases {ds_read quadrant || stage next tile -> barrier ->
// setprio(1) 16 MFMA setprio(0) -> barrier}; vmcnt(0) only at the K-tile
// boundary (loads issued in phases 0-1 -> ~2.5 phases of latency cover).
// LDS read swizzle byte ^= (row&7)<<4 (G4); inverse permutation applied to
// the GLOBAL source address so global_load_lds' linear dest stays valid
// (both-sides-or-neither, rule #21).
// FUSEV: columns >= 2048 (the v slice) are written transposed to
// vT[b][d][s] instead of C (4 rows of a fragment are contiguous in s).
// ---------------------------------------------------------------------------
__device__ __forceinline__ void stage_chunk(
    const _Float16* __restrict__ G, int ldg, int k0, int rowbase,
    _Float16* ldsbase, int chunk, int t) {
  int o16 = chunk * 512 + t;           // linear 16B-chunk index in tile
  int row = o16 >> 3;                  // 8 chunks of 16B per 128B row
  int c = (o16 & 7) ^ (row & 7);       // inverse of the read-side XOR
  gll16(&G[(size_t)(rowbase + row) * ldg + k0 + c * 8],
        (char*)ldsbase + (size_t)o16 * 16);
}

__device__ __forceinline__ f16x8 ldsrd(const _Float16* base, int R, int ech) {
  int byte = R * 128 + ((ech * 16) ^ ((R & 7) << 4));
  return *(const f16x8*)((const char*)base + byte);
}

template <typename OT, bool FUSEV>
__global__ __launch_bounds__(512, 2) void gemm256(
    const _Float16* __restrict__ A, const _Float16* __restrict__ B,
    OT* __restrict__ C, _Float16* __restrict__ vT, int M, int N, int K) {
  __shared__ __align__(16) _Float16 lds[2][2][256][64];  // [dbuf][A,B][row][k]
  int nbm = M >> 8, nbn = N >> 8;
  int nwg = nbm * nbn;
  // bijective XCD swizzle (m204)
  int lin = blockIdx.x;
  int q = nwg >> 3, r = nwg & 7;
  int xcd = lin & 7, orig = lin >> 3;
  int swz = (xcd < r ? xcd * (q + 1) : r * (q + 1) + (xcd - r) * q) + orig;
  int bm = (swz % nbm) * 256, bn = (swz / nbm) * 256;
  (void)nbn;
  int t = threadIdx.x;
  int w = t >> 6, lane = t & 63, lane15 = lane & 15, quad = lane >> 4;
  int wm = w >> 2, wn = w & 3;
  f32x4 acc[8][4] = {};
  int NT = K >> 6;
  // prologue: stage K-tile 0 into buf 0
#pragma unroll
  for (int c = 0; c < 4; c++) {
    stage_chunk(A, K, 0, bm, &lds[0][0][0][0], c, t);
    stage_chunk(B, K, 0, bn, &lds[0][1][0][0], c, t);
  }
  asm volatile("s_waitcnt vmcnt(0)" ::: "memory");
  __builtin_amdgcn_s_barrier();
  __builtin_amdgcn_sched_barrier(0);
  for (int kt = 0; kt < NT; kt++) {
    int cur = kt & 1, nxt = cur ^ 1;
    int k1 = (kt + 1) << 6;
    bool prefetch = (kt + 1 < NT);
#pragma unroll
    for (int ph = 0; ph < 4; ph++) {
      int mh = ph >> 1, nh = ph & 1;
      // 12 ds_read_b128: this phase's output-quadrant fragments
      f16x8 af[2][4], bf[2][2];
#pragma unroll
      for (int ks = 0; ks < 2; ks++) {
#pragma unroll
        for (int i = 0; i < 4; i++)
          af[ks][i] = ldsrd(&lds[cur][0][0][0],
                            wm * 128 + (mh * 4 + i) * 16 + lane15, ks * 4 + quad);
#pragma unroll
        for (int j = 0; j < 2; j++)
          bf[ks][j] = ldsrd(&lds[cur][1][0][0],
                            wn * 64 + (nh * 2 + j) * 16 + lane15, ks * 4 + quad);
      }
      // stage next K-tile (all 8 chunks over phases 0-1 for vmcnt cover)
      if (prefetch && ph < 2) {
#pragma unroll
        for (int c = 0; c < 2; c++) {
          stage_chunk(A, K, k1, bm, &lds[nxt][0][0][0], ph * 2 + c, t);
          stage_chunk(B, K, k1, bn, &lds[nxt][1][0][0], ph * 2 + c, t);
        }
      }
      __builtin_amdgcn_s_barrier();
      __builtin_amdgcn_s_setprio(1);
#pragma unroll
      for (int ks = 0; ks < 2; ks++)
#pragma unroll
        for (int i = 0; i < 4; i++)
#pragma unroll
          for (int j = 0; j < 2; j++)
            acc[mh * 4 + i][nh * 2 + j] = __builtin_amdgcn_mfma_f32_16x16x32_f16(
                af[ks][i], bf[ks][j], acc[mh * 4 + i][nh * 2 + j], 0, 0, 0);
      __builtin_amdgcn_s_setprio(0);
      if (ph == 3 && prefetch)
        asm volatile("s_waitcnt vmcnt(0)" ::: "memory");  // next tile landed
      __builtin_amdgcn_s_barrier();
      __builtin_amdgcn_sched_barrier(0);
    }
  }
  // epilogue
#pragma unroll
  for (int i = 0; i < 8; i++)
#pragma unroll
    for (int j = 0; j < 4; j++) {
      int gr = bm + wm * 128 + i * 16 + quad * 4;
      int gc = bn + wn * 64 + j * 16 + lane15;
      bool tov = false;
      if constexpr (FUSEV) tov = (gc >= 2 * NHEAD * DHEAD);
      if (tov) {
        int b = gr >> 10, s = gr & 1023, d = gc - 2 * NHEAD * DHEAD;
        _Float16 h4[4];
        for (int r2 = 0; r2 < 4; r2++) h4[r2] = (_Float16)acc[i][j][r2];
        *(uint2*)&vT[((size_t)(b * DHEAD + d)) * SEQ + s] = *(uint2*)h4;
      } else {
        for (int r2 = 0; r2 < 4; r2++) {
          float v = acc[i][j][r2];
          if constexpr (std::is_same_v<OT, float>)
            C[(size_t)(gr + r2) * N + gc] = v;
          else
            C[(size_t)(gr + r2) * N + gc] = (_Float16)v;
        }
      }
    }
}

// ---------------------------------------------------------------------------
// Scores + softmax. DEFERRED softmax: phase A runs all QK^T MFMAs with a
// double-buffered K pipeline; phase B does ONE max/exp/sum pass over the
// register-resident strip. XCD-chunked block swizzle for K-slice L2 reuse.
// Grid (SEQ/64, NHEAD, BATCH), 512 thr = 4 row-grp x 2 col-half.
// ---------------------------------------------------------------------------
__global__ __launch_bounds__(512, 2) void scores_norm_kernel(
    const _Float16* __restrict__ qkv, float* __restrict__ P) {
  int lin = blockIdx.x + 16 * (blockIdx.y + 4 * blockIdx.z);
  int swz = (lin & 7) * 128 + (lin >> 3);
  int ti = swz & 15, n = (swz >> 4) & 3, b = swz >> 6;
  __shared__ __align__(16) _Float16 Qs[8][64][32];
  __shared__ __align__(16) _Float16 Ks[2][8][64][32];
  int t = threadIdx.x;
  int w = t >> 6, L = t & 63, lane15 = L & 15, quad = L >> 4;
  int r16 = (w & 3) * 16;   // row group
  int ch  = (w >> 2) * 32;  // col half
  for (int r = 0; r < 4; r++) {
    int u = t + r * 512;
    int kc = u >> 8, row = (u & 255) >> 2, c8 = u & 3;
    gll16(&qkv[((size_t)(b * SEQ + ti * 64 + row)) * QKVN + n * DHEAD + kc * 32 + c8 * 8],
          &Qs[kc][row][c8 * 8]);
    gll16(&qkv[((size_t)(b * SEQ + row)) * QKVN + NHEAD * DHEAD + n * DHEAD + kc * 32 + c8 * 8],
          &Ks[0][kc][row][c8 * 8]);
  }
  __syncthreads();
  f16x8 aq[8];
#pragma unroll
  for (int kc = 0; kc < 8; kc++) aq[kc] = *(f16x8*)&Qs[kc][r16 + lane15][quad * 8];
  f32x4 s[16][2];
  int trow = ti * 64 + r16 + quad * 4;
  const float scale = 0.0625f;
#pragma unroll
  for (int si = 0; si < 16; si++) {
    if (si <= ti) {
      if (si < ti) {
        for (int r = 0; r < 4; r++) {
          int u = t + r * 512;
          int kc = u >> 8, row = (u & 255) >> 2, c8 = u & 3;
          gll16(&qkv[((size_t)(b * SEQ + (si + 1) * 64 + row)) * QKVN + NHEAD * DHEAD + n * DHEAD + kc * 32 + c8 * 8],
                &Ks[(si + 1) & 1][kc][row][c8 * 8]);
        }
      }
      s[si][0] = (f32x4){0.f, 0.f, 0.f, 0.f};
      s[si][1] = (f32x4){0.f, 0.f, 0.f, 0.f};
      for (int kc = 0; kc < 8; kc++) {
        for (int j = 0; j < 2; j++) {
          f16x8 bk = *(f16x8*)&Ks[si & 1][kc][ch + j * 16 + lane15][quad * 8];
          s[si][j] = __builtin_amdgcn_mfma_f32_16x16x32_f16(aq[kc], bk, s[si][j], 0, 0, 0);
        }
      }
      __syncthreads();
    }
  }
  float m[4], l[4];
#pragma unroll
  for (int r = 0; r < 4; r++) {
    float mx = -INFINITY;
#pragma unroll
    for (int si = 0; si < 16; si++) {
      if (si <= ti) {
        for (int j = 0; j < 2; j++) {
          int col = si * 64 + ch + j * 16 + lane15;
          float v = s[si][j][r] * scale;
          if (col > trow + r) v = -1e9f;
          s[si][j][r] = v;
          mx = fmaxf(mx, v);
        }
      }
    }
    for (int off = 1; off < 16; off <<= 1) mx = fmaxf(mx, __shfl_xor(mx, off, 64));
    float sum = 0.f;
#pragma unroll
    for (int si = 0; si < 16; si++) {
      if (si <= ti) {
        for (int j = 0; j < 2; j++) {
          float p = __expf(s[si][j][r] - mx);
          s[si][j][r] = p;
          sum += p;
        }
      }
    }
    for (int off = 1; off < 16; off <<= 1) sum += __shfl_xor(sum, off, 64);
    m[r] = mx; l[r] = sum;
  }
  __syncthreads();
  float* sM  = (float*)&Qs[0][0][0];
  float* sL  = sM + 128;
  float* sMc = sM + 256;
  float* sRl = sM + 320;
  if (lane15 == 0) {
    for (int r = 0; r < 4; r++) {
      sM[(w >> 2) * 64 + r16 + quad * 4 + r] = m[r];
      sL[(w >> 2) * 64 + r16 + quad * 4 + r] = l[r];
    }
  }
  __syncthreads();
  if (t < 64) {
    float m0 = sM[t], m1 = sM[64 + t], l0 = sL[t], l1 = sL[64 + t];
    float mc = fmaxf(m0, m1);
    float lc = l0 * __expf(m0 - mc) + l1 * __expf(m1 - mc);
    sMc[t] = mc;
    sRl[t] = 1.0f / lc;
  }
  __syncthreads();
  float fac[4];
  for (int r = 0; r < 4; r++) {
    int row = r16 + quad * 4 + r;
    fac[r] = __expf(m[r] - sMc[row]) * sRl[row];
  }
  size_t Pbase = ((size_t)(b * NHEAD + n)) * SEQ * SEQ;
#pragma unroll
  for (int si = 0; si < 16; si++) {
    if (si <= ti) {
      for (int j = 0; j < 2; j++) {
        int col = si * 64 + ch + j * 16 + lane15;
        for (int r = 0; r < 4; r++)
          P[Pbase + (size_t)(trow + r) * SEQ + col] = s[si][j][r] * fac[r];
      }
    }
  }
  {
    float4 z = make_float4(0.f, 0.f, 0.f, 0.f);
    int c4min = (ti + 1) * 16;
    for (int u = t; u < 16384; u += 512) {
      int row = u >> 8, c4 = u & 255;
      if (c4 >= c4min)
        *(float4*)&P[Pbase + (size_t)(ti * 64 + row) * SEQ + c4 * 4] = z;
    }
  }
}

// ---------------------------------------------------------------------------
// Pmean[b][t][s] = f16( mean_n P[b][n][t][s] ), causal tiles only.
// ---------------------------------------------------------------------------
__global__ __launch_bounds__(256) void pmean_kernel(
    const float* __restrict__ P, _Float16* __restrict__ Pmean) {
  int si = blockIdx.x, ti = blockIdx.y, b = blockIdx.z;
  if (si > ti) return;
  int t = threadIdx.x;
  int row = t >> 2, c16 = (t & 3) * 16;
  size_t tile_off = (size_t)(ti * 64 + row) * SEQ + si * 64 + c16;
  float acc[16];
  for (int i = 0; i < 16; i++) acc[i] = 0.f;
  for (int n = 0; n < 4; n++) {
    const float* p = &P[((size_t)(b * NHEAD + n)) * SEQ * SEQ + tile_off];
    for (int q = 0; q < 4; q++) {
      float4 v = *(const float4*)(p + q * 4);
      acc[q * 4 + 0] += v.x; acc[q * 4 + 1] += v.y;
      acc[q * 4 + 2] += v.z; acc[q * 4 + 3] += v.w;
    }
  }
  _Float16 h[16];
  for (int i = 0; i < 16; i++) h[i] = (_Float16)(acc[i] * 0.25f);
  _Float16* pm = &Pmean[((size_t)(b * SEQ + ti * 64 + row)) * SEQ + si * 64 + c16];
  *(uint4*)pm = *(uint4*)h;
  *(uint4*)(pm + 8) = *(uint4*)(h + 8);
}

// ---------------------------------------------------------------------------
// m_attn[b][t][d] = sum_s Pmean[b][t][s] * v[b][s][d]  (f16 out)
// Grid (ti, d-quarter, b), double-buffered si loop, XCD-chunked swizzle.
// ---------------------------------------------------------------------------
__global__ __launch_bounds__(256) void pv_kernel(
    const _Float16* __restrict__ Pmean, const _Float16* __restrict__ vT,
    _Float16* __restrict__ mattn) {
  int lin = blockIdx.x + 16 * (blockIdx.y + 4 * blockIdx.z);
  int swz = (lin & 7) * 128 + (lin >> 3);
  int ti = swz & 15, dq = (swz >> 4) & 3, b = swz >> 6;
  __shared__ __align__(16) _Float16 Pm[2][2][64][32];
  __shared__ __align__(16) _Float16 Vs[2][2][64][32];
  int t = threadIdx.x;
  int w = t >> 6, L = t & 63, lane15 = L & 15, quad = L >> 4;
  f32x4 acc[4] = {};
  for (int r = 0; r < 2; r++) {
    int u = t + r * 256;
    int kc = u >> 8, row = (u & 255) >> 2, c8 = u & 3;
    gll16(&Pmean[((size_t)(b * SEQ + ti * 64 + row)) * SEQ + kc * 32 + c8 * 8],
          &Pm[0][kc][row][c8 * 8]);
    gll16(&vT[((size_t)(b * DHEAD + dq * 64 + row)) * SEQ + kc * 32 + c8 * 8],
          &Vs[0][kc][row][c8 * 8]);
  }
  __syncthreads();
  for (int si = 0; si <= ti; si++) {
    int cb = si & 1;
    if (si < ti) {
      for (int r = 0; r < 2; r++) {
        int u = t + r * 256;
        int kc = u >> 8, row = (u & 255) >> 2, c8 = u & 3;
        gll16(&Pmean[((size_t)(b * SEQ + ti * 64 + row)) * SEQ + (si + 1) * 64 + kc * 32 + c8 * 8],
              &Pm[cb ^ 1][kc][row][c8 * 8]);
        gll16(&vT[((size_t)(b * DHEAD + dq * 64 + row)) * SEQ + (si + 1) * 64 + kc * 32 + c8 * 8],
              &Vs[cb ^ 1][kc][row][c8 * 8]);
      }
    }
#pragma unroll
    for (int kc = 0; kc < 2; kc++) {
      f16x8 ap = *(f16x8*)&Pm[cb][kc][w * 16 + lane15][quad * 8];
#pragma unroll
      for (int j = 0; j < 4; j++) {
        f16x8 bv = *(f16x8*)&Vs[cb][kc][j * 16 + lane15][quad * 8];
        acc[j] = __builtin_amdgcn_mfma_f32_16x16x32_f16(ap, bv, acc[j], 0, 0, 0);
      }
    }
    __syncthreads();
  }
  for (int j = 0; j < 4; j++) {
    int row = b * SEQ + ti * 64 + w * 16 + quad * 4;
    int col = dq * 64 + j * 16 + lane15;
    for (int r = 0; r < 4; r++)
      mattn[(size_t)(row + r) * DHEAD + col] = (_Float16)acc[j][r];
  }
}

// ---------------------------------------------------------------------------
// ws layout (f16 elems): wqkvT[2304*1024] | woutT[1024*256] | qkvb[16384*2304]
// | vT[16*256*1024].  After scores, qkvb is dead -> mattn = qkvb,
// Pmean = qkvb + 16384*256.  xh (x as f16) lives in P region until scores.
// ---------------------------------------------------------------------------
extern "C" void kernel_launch(void* const* d_in, const int* in_sizes, int n_in,
                              void* d_out, int out_size, void* d_ws, size_t ws_size,
                              hipStream_t stream) {
  const float* x     = (const float*)d_in[0];
  const float* w_qkv = (const float*)d_in[1];
  const float* w_out = (const float*)d_in[2];
  float* out = (float*)d_out;
  float* P   = out + (size_t)BATCH * SEQ * HIDDEN;

  _Float16* wqkvT = (_Float16*)d_ws;
  _Float16* woutT = wqkvT + (size_t)QKVN * HIDDEN;
  _Float16* qkvb  = woutT + (size_t)HIDDEN * DHEAD;
  _Float16* vT    = qkvb + (size_t)BATCH * SEQ * QKVN;
  _Float16* mattn = qkvb;                              // alias (qkvb dead after scores)
  _Float16* Pmean = qkvb + (size_t)BATCH * SEQ * DHEAD;
  _Float16* xh    = (_Float16*)P;                      // alias (overwritten by scores)

  f32_to_f16<<<BATCH * SEQ * HIDDEN / 1024, 256, 0, stream>>>(x, xh);
  transpose_to_f16<<<dim3(QKVN / 64, HIDDEN / 64), 256, 0, stream>>>(w_qkv, wqkvT, HIDDEN, QKVN);
  transpose_to_f16<<<dim3(HIDDEN / 64, DHEAD / 64), 256, 0, stream>>>(w_out, woutT, DHEAD, HIDDEN);
  // qkv GEMM (writes q,k to qkvb; v written transposed straight to vT)
  gemm256<_Float16, true><<<(BATCH * SEQ / 256) * (QKVN / 256), 512, 0, stream>>>(
      xh, wqkvT, qkvb, vT, BATCH * SEQ, QKVN, HIDDEN);
  scores_norm_kernel<<<dim3(SEQ / 64, NHEAD, BATCH), 512, 0, stream>>>(qkvb, P);
  pmean_kernel<<<dim3(SEQ / 64, SEQ / 64, BATCH), 256, 0, stream>>>(P, Pmean);
  pv_kernel<<<dim3(SEQ / 64, 4, BATCH), 256, 0, stream>>>(Pmean, vT, mattn);
  gemm256<float, false><<<(BATCH * SEQ / 256) * (HIDDEN / 256), 512, 0, stream>>>(
      mattn, woutT, out, nullptr, BATCH * SEQ, HIDDEN, DHEAD);
}

// Round 3
// 634.670 us; speedup vs baseline: 1.0126x; 1.0126x over previous
//
#include <hip/hip_runtime.h>
#include <hip/hip_bf16.h>
#include <type_traits>

#define BATCH  16
#define SEQ    1024
#define HIDDEN 1024
#define NHEAD  4
#define DHEAD  256
#define QKVN   2304   // (2*NHEAD+1)*DHEAD

typedef _Float16 f16x8 __attribute__((ext_vector_type(8)));
typedef float    f32x4 __attribute__((ext_vector_type(4)));

__device__ __forceinline__ void gll16(const void* g, void* l) {
  __builtin_amdgcn_global_load_lds(
      (const __attribute__((address_space(1))) unsigned int*)g,
      (__attribute__((address_space(3))) unsigned int*)l, 16, 0, 0);
}

// ---------------------------------------------------------------------------
// Fused prep: f32->f16 conversion of x (blocks [0,16384)), w_qkv transpose
// (blocks [16384,16960)), w_out transpose (blocks [16960,17024)).
// ---------------------------------------------------------------------------
__global__ __launch_bounds__(256) void prep_kernel(
    const float* __restrict__ x, _Float16* __restrict__ xh,
    const float* __restrict__ w_qkv, _Float16* __restrict__ wqkvT,
    const float* __restrict__ w_out, _Float16* __restrict__ woutT) {
  __shared__ float tile[64][65];
  int bid = blockIdx.x;
  int t = threadIdx.x;
  if (bid < 16384) {
    int i4 = bid * 256 + t;
    float4 v = ((const float4*)x)[i4];
    _Float16 h4[4] = {(_Float16)v.x, (_Float16)v.y, (_Float16)v.z, (_Float16)v.w};
    *(uint2*)&xh[(size_t)i4 * 4] = *(uint2*)h4;
    return;
  }
  const float* in; _Float16* out; int R, C, bx, by;
  if (bid < 16384 + 576) {
    int u = bid - 16384;
    in = w_qkv; out = wqkvT; R = HIDDEN; C = QKVN;
    bx = u % 36; by = u / 36;
  } else {
    int u = bid - 16960;
    in = w_out; out = woutT; R = DHEAD; C = HIDDEN;
    bx = u % 16; by = u / 16;
  }
  int bc = bx * 64, br = by * 64;
  int tr = t >> 6, tc = t & 63;
  for (int i = 0; i < 64; i += 4)
    tile[tr + i][tc] = in[(size_t)(br + tr + i) * C + bc + tc];
  __syncthreads();
  for (int i = 0; i < 64; i += 4)
    out[(size_t)(bc + tr + i) * R + br + tc] = (_Float16)tile[tc][tr + i];
}

// ---------------------------------------------------------------------------
// 256x256-tile 8-phase GEMM (B^T): C[m][n] = sum_k A[m][k]*B[n][k], f16 in.
// (unchanged from R2 — neutral vs gemm_bt+transpose_v but one fewer kernel)
// ---------------------------------------------------------------------------
__device__ __forceinline__ void stage_chunk(
    const _Float16* __restrict__ G, int ldg, int k0, int rowbase,
    _Float16* ldsbase, int chunk, int t) {
  int o16 = chunk * 512 + t;           // linear 16B-chunk index in tile
  int row = o16 >> 3;                  // 8 chunks of 16B per 128B row
  int c = (o16 & 7) ^ (row & 7);       // inverse of the read-side XOR
  gll16(&G[(size_t)(rowbase + row) * ldg + k0 + c * 8],
        (char*)ldsbase + (size_t)o16 * 16);
}

__device__ __forceinline__ f16x8 ldsrd(const _Float16* base, int R, int ech) {
  int byte = R * 128 + ((ech * 16) ^ ((R & 7) << 4));
  return *(const f16x8*)((const char*)base + byte);
}

template <typename OT, bool FUSEV>
__global__ __launch_bounds__(512, 2) void gemm256(
    const _Float16* __restrict__ A, const _Float16* __restrict__ B,
    OT* __restrict__ C, _Float16* __restrict__ vT, int M, int N, int K) {
  __shared__ __align__(16) _Float16 lds[2][2][256][64];  // [dbuf][A,B][row][k]
  int nbm = M >> 8, nbn = N >> 8;
  int nwg = nbm * nbn;
  int lin = blockIdx.x;
  int q = nwg >> 3, r = nwg & 7;
  int xcd = lin & 7, orig = lin >> 3;
  int swz = (xcd < r ? xcd * (q + 1) : r * (q + 1) + (xcd - r) * q) + orig;
  int bm = (swz % nbm) * 256, bn = (swz / nbm) * 256;
  (void)nbn;
  int t = threadIdx.x;
  int w = t >> 6, lane = t & 63, lane15 = lane & 15, quad = lane >> 4;
  int wm = w >> 2, wn = w & 3;
  f32x4 acc[8][4] = {};
  int NT = K >> 6;
#pragma unroll
  for (int c = 0; c < 4; c++) {
    stage_chunk(A, K, 0, bm, &lds[0][0][0][0], c, t);
    stage_chunk(B, K, 0, bn, &lds[0][1][0][0], c, t);
  }
  asm volatile("s_waitcnt vmcnt(0)" ::: "memory");
  __builtin_amdgcn_s_barrier();
  __builtin_amdgcn_sched_barrier(0);
  for (int kt = 0; kt < NT; kt++) {
    int cur = kt & 1, nxt = cur ^ 1;
    int k1 = (kt + 1) << 6;
    bool prefetch = (kt + 1 < NT);
#pragma unroll
    for (int ph = 0; ph < 4; ph++) {
      int mh = ph >> 1, nh = ph & 1;
      f16x8 af[2][4], bf[2][2];
#pragma unroll
      for (int ks = 0; ks < 2; ks++) {
#pragma unroll
        for (int i = 0; i < 4; i++)
          af[ks][i] = ldsrd(&lds[cur][0][0][0],
                            wm * 128 + (mh * 4 + i) * 16 + lane15, ks * 4 + quad);
#pragma unroll
        for (int j = 0; j < 2; j++)
          bf[ks][j] = ldsrd(&lds[cur][1][0][0],
                            wn * 64 + (nh * 2 + j) * 16 + lane15, ks * 4 + quad);
      }
      if (prefetch && ph < 2) {
#pragma unroll
        for (int c = 0; c < 2; c++) {
          stage_chunk(A, K, k1, bm, &lds[nxt][0][0][0], ph * 2 + c, t);
          stage_chunk(B, K, k1, bn, &lds[nxt][1][0][0], ph * 2 + c, t);
        }
      }
      __builtin_amdgcn_s_barrier();
      __builtin_amdgcn_s_setprio(1);
#pragma unroll
      for (int ks = 0; ks < 2; ks++)
#pragma unroll
        for (int i = 0; i < 4; i++)
#pragma unroll
          for (int j = 0; j < 2; j++)
            acc[mh * 4 + i][nh * 2 + j] = __builtin_amdgcn_mfma_f32_16x16x32_f16(
                af[ks][i], bf[ks][j], acc[mh * 4 + i][nh * 2 + j], 0, 0, 0);
      __builtin_amdgcn_s_setprio(0);
      if (ph == 3 && prefetch)
        asm volatile("s_waitcnt vmcnt(0)" ::: "memory");
      __builtin_amdgcn_s_barrier();
      __builtin_amdgcn_sched_barrier(0);
    }
  }
#pragma unroll
  for (int i = 0; i < 8; i++)
#pragma unroll
    for (int j = 0; j < 4; j++) {
      int gr = bm + wm * 128 + i * 16 + quad * 4;
      int gc = bn + wn * 64 + j * 16 + lane15;
      bool tov = false;
      if constexpr (FUSEV) tov = (gc >= 2 * NHEAD * DHEAD);
      if (tov) {
        int b = gr >> 10, s = gr & 1023, d = gc - 2 * NHEAD * DHEAD;
        _Float16 h4[4];
        for (int r2 = 0; r2 < 4; r2++) h4[r2] = (_Float16)acc[i][j][r2];
        *(uint2*)&vT[((size_t)(b * DHEAD + d)) * SEQ + s] = *(uint2*)h4;
      } else {
        for (int r2 = 0; r2 < 4; r2++) {
          float v = acc[i][j][r2];
          if constexpr (std::is_same_v<OT, float>)
            C[(size_t)(gr + r2) * N + gc] = v;
          else
            C[(size_t)(gr + r2) * N + gc] = (_Float16)v;
        }
      }
    }
}

// ---------------------------------------------------------------------------
// Scores + softmax (deferred). R3: depth-2 K pipeline with 3 LDS buffers,
// counted vmcnt ladder (8/4/0) + raw s_barrier pairs (no full drain per
// tile), Q fragments gathered directly from global (Qs LDS removed),
// setprio around the MFMA cluster. Grid (SEQ/64, NHEAD, BATCH), 512 thr.
// Race ledger: tile si reads Ks[si%3]; STAGE(si+2)->Ks[(si+2)%3] is issued
// only after bar2 of iter si-1 (all waves' ds_reads of that buffer have
// completed in-order before their bar2); vmcnt ladder waits exactly tile
// si's 4 per-thread gll16s (outstanding = 8 steady / 4 tail / 0 last).
// ---------------------------------------------------------------------------
__global__ __launch_bounds__(512, 2) void scores_norm_kernel(
    const _Float16* __restrict__ qkv, float* __restrict__ P) {
  int lin = blockIdx.x + 16 * (blockIdx.y + 4 * blockIdx.z);
  int swz = (lin & 7) * 128 + (lin >> 3);
  int ti = swz & 15, n = (swz >> 4) & 3, b = swz >> 6;
  __shared__ __align__(16) _Float16 Ks[3][8][64][32];
  __shared__ float scratch[384];
  int t = threadIdx.x;
  int w = t >> 6, L = t & 63, lane15 = L & 15, quad = L >> 4;
  int r16 = (w & 3) * 16;   // row group
  int ch  = (w >> 2) * 32;  // col half
  // Q fragments: one-time 16B/lane global gather (frees 32 KB LDS)
  f16x8 aq[8];
#pragma unroll
  for (int kc = 0; kc < 8; kc++)
    aq[kc] = *(const f16x8*)&qkv[((size_t)(b * SEQ + ti * 64 + r16 + lane15)) * QKVN
                                 + n * DHEAD + kc * 32 + quad * 8];
  asm volatile("s_waitcnt vmcnt(0)" ::: "memory");  // keep vmcnt ladder exact

#define STAGEK(si_, buf_)                                                     \
  for (int r_ = 0; r_ < 4; r_++) {                                            \
    int u_ = t + r_ * 512;                                                    \
    int kc_ = u_ >> 8, row_ = (u_ & 255) >> 2, c8_ = u_ & 3;                  \
    gll16(&qkv[((size_t)(b * SEQ + (si_) * 64 + row_)) * QKVN                 \
               + NHEAD * DHEAD + n * DHEAD + kc_ * 32 + c8_ * 8],             \
          &Ks[buf_][kc_][row_][c8_ * 8]);                                     \
  }

  // prologue: stage tiles 0 and 1
  STAGEK(0, 0);
  if (ti >= 1) STAGEK(1, 1);

  f32x4 s[16][2];
  int trow = ti * 64 + r16 + quad * 4;
  const float scale = 0.0625f;
#pragma unroll
  for (int si = 0; si < 16; si++) {
    if (si <= ti) {
      if (si + 2 <= ti) { STAGEK(si + 2, (si + 2) % 3); }
      int d = ti - si;
      if (d >= 2)      asm volatile("s_waitcnt vmcnt(8)" ::: "memory");
      else if (d == 1) asm volatile("s_waitcnt vmcnt(4)" ::: "memory");
      else             asm volatile("s_waitcnt vmcnt(0)" ::: "memory");
      __builtin_amdgcn_s_barrier();
      __builtin_amdgcn_sched_barrier(0);
      s[si][0] = (f32x4){0.f, 0.f, 0.f, 0.f};
      s[si][1] = (f32x4){0.f, 0.f, 0.f, 0.f};
      __builtin_amdgcn_s_setprio(1);
#pragma unroll
      for (int kc = 0; kc < 8; kc++) {
#pragma unroll
        for (int j = 0; j < 2; j++) {
          f16x8 bk = *(f16x8*)&Ks[si % 3][kc][ch + j * 16 + lane15][quad * 8];
          s[si][j] = __builtin_amdgcn_mfma_f32_16x16x32_f16(aq[kc], bk, s[si][j], 0, 0, 0);
        }
      }
      __builtin_amdgcn_s_setprio(0);
      __builtin_amdgcn_s_barrier();
      __builtin_amdgcn_sched_barrier(0);
    }
  }
#undef STAGEK
  // ---- deferred softmax, one pass over the register strip ----
  float m[4], l[4];
#pragma unroll
  for (int r = 0; r < 4; r++) {
    float mx = -INFINITY;
#pragma unroll
    for (int si = 0; si < 16; si++) {
      if (si <= ti) {
        for (int j = 0; j < 2; j++) {
          int col = si * 64 + ch + j * 16 + lane15;
          float v = s[si][j][r] * scale;
          if (col > trow + r) v = -1e9f;
          s[si][j][r] = v;
          mx = fmaxf(mx, v);
        }
      }
    }
    for (int off = 1; off < 16; off <<= 1) mx = fmaxf(mx, __shfl_xor(mx, off, 64));
    float sum = 0.f;
#pragma unroll
    for (int si = 0; si < 16; si++) {
      if (si <= ti) {
        for (int j = 0; j < 2; j++) {
          float p = __expf(s[si][j][r] - mx);
          s[si][j][r] = p;
          sum += p;
        }
      }
    }
    for (int off = 1; off < 16; off <<= 1) sum += __shfl_xor(sum, off, 64);
    m[r] = mx; l[r] = sum;
  }
  // merge the two col-halves' stats per row via LDS scratch
  __syncthreads();
  float* sM  = scratch;        // [2][64]
  float* sL  = scratch + 128;
  float* sMc = scratch + 256;  // [64] merged max
  float* sRl = scratch + 320;  // [64] merged 1/l
  if (lane15 == 0) {
    for (int r = 0; r < 4; r++) {
      sM[(w >> 2) * 64 + r16 + quad * 4 + r] = m[r];
      sL[(w >> 2) * 64 + r16 + quad * 4 + r] = l[r];
    }
  }
  __syncthreads();
  if (t < 64) {
    float m0 = sM[t], m1 = sM[64 + t], l0 = sL[t], l1 = sL[64 + t];
    float mc = fmaxf(m0, m1);
    float lc = l0 * __expf(m0 - mc) + l1 * __expf(m1 - mc);
    sMc[t] = mc;
    sRl[t] = 1.0f / lc;
  }
  __syncthreads();
  float fac[4];
  for (int r = 0; r < 4; r++) {
    int row = r16 + quad * 4 + r;
    fac[r] = __expf(m[r] - sMc[row]) * sRl[row];
  }
  size_t Pbase = ((size_t)(b * NHEAD + n)) * SEQ * SEQ;
#pragma unroll
  for (int si = 0; si < 16; si++) {
    if (si <= ti) {
      for (int j = 0; j < 2; j++) {
        int col = si * 64 + ch + j * 16 + lane15;
        for (int r = 0; r < 4; r++)
          P[Pbase + (size_t)(trow + r) * SEQ + col] = s[si][j][r] * fac[r];
      }
    }
  }
  {
    float4 z = make_float4(0.f, 0.f, 0.f, 0.f);
    int c4min = (ti + 1) * 16;
    for (int u = t; u < 16384; u += 512) {
      int row = u >> 8, c4 = u & 255;
      if (c4 >= c4min)
        *(float4*)&P[Pbase + (size_t)(ti * 64 + row) * SEQ + c4 * 4] = z;
    }
  }
}

// ---------------------------------------------------------------------------
// Pmean[b][t][s] = f16( mean_n P[b][n][t][s] ), causal tiles only.
// R3: exact triangular 1D grid (136 causal tiles x 16 batches) — no
// early-exit null blocks.
// ---------------------------------------------------------------------------
__global__ __launch_bounds__(256) void pmean_kernel(
    const float* __restrict__ P, _Float16* __restrict__ Pmean) {
  int u = blockIdx.x, b = blockIdx.y;
  int ti = (int)((__fsqrt_rn(8.f * u + 1.f) - 1.f) * 0.5f);
  while ((ti + 1) * (ti + 2) / 2 <= u) ++ti;
  while (ti * (ti + 1) / 2 > u) --ti;
  int si = u - ti * (ti + 1) / 2;
  int t = threadIdx.x;
  int row = t >> 2, c16 = (t & 3) * 16;
  size_t tile_off = (size_t)(ti * 64 + row) * SEQ + si * 64 + c16;
  float acc[16];
  for (int i = 0; i < 16; i++) acc[i] = 0.f;
  for (int n = 0; n < 4; n++) {
    const float* p = &P[((size_t)(b * NHEAD + n)) * SEQ * SEQ + tile_off];
    for (int q = 0; q < 4; q++) {
      float4 v = *(const float4*)(p + q * 4);
      acc[q * 4 + 0] += v.x; acc[q * 4 + 1] += v.y;
      acc[q * 4 + 2] += v.z; acc[q * 4 + 3] += v.w;
    }
  }
  _Float16 h[16];
  for (int i = 0; i < 16; i++) h[i] = (_Float16)(acc[i] * 0.25f);
  _Float16* pm = &Pmean[((size_t)(b * SEQ + ti * 64 + row)) * SEQ + si * 64 + c16];
  *(uint4*)pm = *(uint4*)h;
  *(uint4*)(pm + 8) = *(uint4*)(h + 8);
}

// ---------------------------------------------------------------------------
// m_attn[b][t][d] = sum_s Pmean[b][t][s] * v[b][s][d]  (f16 out)
// Grid (ti, d-quarter, b), double-buffered si loop, XCD-chunked swizzle.
// ---------------------------------------------------------------------------
__global__ __launch_bounds__(256) void pv_kernel(
    const _Float16* __restrict__ Pmean, const _Float16* __restrict__ vT,
    _Float16* __restrict__ mattn) {
  int lin = blockIdx.x + 16 * (blockIdx.y + 4 * blockIdx.z);
  int swz = (lin & 7) * 128 + (lin >> 3);
  int ti = swz & 15, dq = (swz >> 4) & 3, b = swz >> 6;
  __shared__ __align__(16) _Float16 Pm[2][2][64][32];
  __shared__ __align__(16) _Float16 Vs[2][2][64][32];
  int t = threadIdx.x;
  int w = t >> 6, L = t & 63, lane15 = L & 15, quad = L >> 4;
  f32x4 acc[4] = {};
  for (int r = 0; r < 2; r++) {
    int u = t + r * 256;
    int kc = u >> 8, row = (u & 255) >> 2, c8 = u & 3;
    gll16(&Pmean[((size_t)(b * SEQ + ti * 64 + row)) * SEQ + kc * 32 + c8 * 8],
          &Pm[0][kc][row][c8 * 8]);
    gll16(&vT[((size_t)(b * DHEAD + dq * 64 + row)) * SEQ + kc * 32 + c8 * 8],
          &Vs[0][kc][row][c8 * 8]);
  }
  __syncthreads();
  for (int si = 0; si <= ti; si++) {
    int cb = si & 1;
    if (si < ti) {
      for (int r = 0; r < 2; r++) {
        int u = t + r * 256;
        int kc = u >> 8, row = (u & 255) >> 2, c8 = u & 3;
        gll16(&Pmean[((size_t)(b * SEQ + ti * 64 + row)) * SEQ + (si + 1) * 64 + kc * 32 + c8 * 8],
              &Pm[cb ^ 1][kc][row][c8 * 8]);
        gll16(&vT[((size_t)(b * DHEAD + dq * 64 + row)) * SEQ + (si + 1) * 64 + kc * 32 + c8 * 8],
              &Vs[cb ^ 1][kc][row][c8 * 8]);
      }
    }
#pragma unroll
    for (int kc = 0; kc < 2; kc++) {
      f16x8 ap = *(f16x8*)&Pm[cb][kc][w * 16 + lane15][quad * 8];
#pragma unroll
      for (int j = 0; j < 4; j++) {
        f16x8 bv = *(f16x8*)&Vs[cb][kc][j * 16 + lane15][quad * 8];
        acc[j] = __builtin_amdgcn_mfma_f32_16x16x32_f16(ap, bv, acc[j], 0, 0, 0);
      }
    }
    __syncthreads();
  }
  for (int j = 0; j < 4; j++) {
    int row = b * SEQ + ti * 64 + w * 16 + quad * 4;
    int col = dq * 64 + j * 16 + lane15;
    for (int r = 0; r < 4; r++)
      mattn[(size_t)(row + r) * DHEAD + col] = (_Float16)acc[j][r];
  }
}

// ---------------------------------------------------------------------------
// ws layout (f16 elems): wqkvT[2304*1024] | woutT[1024*256] | qkvb[16384*2304]
// | vT[16*256*1024].  After scores, qkvb is dead -> mattn = qkvb,
// Pmean = qkvb + 16384*256.  xh (x as f16) lives in P region until scores.
// ---------------------------------------------------------------------------
extern "C" void kernel_launch(void* const* d_in, const int* in_sizes, int n_in,
                              void* d_out, int out_size, void* d_ws, size_t ws_size,
                              hipStream_t stream) {
  const float* x     = (const float*)d_in[0];
  const float* w_qkv = (const float*)d_in[1];
  const float* w_out = (const float*)d_in[2];
  float* out = (float*)d_out;
  float* P   = out + (size_t)BATCH * SEQ * HIDDEN;

  _Float16* wqkvT = (_Float16*)d_ws;
  _Float16* woutT = wqkvT + (size_t)QKVN * HIDDEN;
  _Float16* qkvb  = woutT + (size_t)HIDDEN * DHEAD;
  _Float16* vT    = qkvb + (size_t)BATCH * SEQ * QKVN;
  _Float16* mattn = qkvb;                              // alias (qkvb dead after scores)
  _Float16* Pmean = qkvb + (size_t)BATCH * SEQ * DHEAD;
  _Float16* xh    = (_Float16*)P;                      // alias (overwritten by scores)

  prep_kernel<<<16384 + 576 + 64, 256, 0, stream>>>(x, xh, w_qkv, wqkvT, w_out, woutT);
  // qkv GEMM (writes q,k to qkvb; v written transposed straight to vT)
  gemm256<_Float16, true><<<(BATCH * SEQ / 256) * (QKVN / 256), 512, 0, stream>>>(
      xh, wqkvT, qkvb, vT, BATCH * SEQ, QKVN, HIDDEN);
  scores_norm_kernel<<<dim3(SEQ / 64, NHEAD, BATCH), 512, 0, stream>>>(qkvb, P);
  pmean_kernel<<<dim3(136, BATCH), 256, 0, stream>>>(P, Pmean);
  pv_kernel<<<dim3(SEQ / 64, 4, BATCH), 256, 0, stream>>>(Pmean, vT, mattn);
  gemm256<float, false><<<(BATCH * SEQ / 256) * (HIDDEN / 256), 512, 0, stream>>>(
      mattn, woutT, out, nullptr, BATCH * SEQ, HIDDEN, DHEAD);
}